// Round 4
// baseline (820.314 us; speedup 1.0000x reference)
//
#include <hip/hip_runtime.h>
#include <hip/hip_bf16.h>

#define NCODES 1024
#define DIMS   256
#define HWSZ   4096
#define NPOS   65536

#define TN 128
#define TK 128
#define CC 16
#define NKC (NCODES / TK)   // 8
#define NCC (DIMS / CC)     // 16

// ws float offsets
#define WS_LOSS 0
#define WS_B    256
#define WS_A    2048
#define WS_CBT  67584        // 2048 + 65536
// total floats: 67584 + 262144 = 329728  (~1.26 MB)

__global__ void prep_kernel(const float* __restrict__ cb, float* __restrict__ ws) {
#pragma clang fp contract(off)
    int k = blockIdx.x * blockDim.x + threadIdx.x;   // 0..1023
    if (k == 0) ws[WS_LOSS] = 0.0f;
    float* bsum = ws + WS_B;
    float* cbT  = ws + WS_CBT;
    if (k < NCODES) {
        float s = 0.0f;
        for (int c = 0; c < DIMS; ++c) {
            float v = cb[k * DIMS + c];
            float p = v * v;          // rounded square (matches cb*cb then sum)
            s = s + p;
            cbT[c * NCODES + k] = v;
        }
        bsum[k] = s;
    }
}

__global__ void a_kernel(const float* __restrict__ z, float* __restrict__ ws) {
#pragma clang fp contract(off)
    int n = blockIdx.x * blockDim.x + threadIdx.x;   // 0..65535
    int b = n >> 12;
    int hw = n & 4095;
    const float* zp = z + (size_t)b * DIMS * HWSZ + hw;
    float s = 0.0f;
    for (int c = 0; c < DIMS; ++c) {
        float v = zp[(size_t)c * HWSZ];
        float p = v * v;              // rounded square, sequential sum
        s = s + p;
    }
    ws[WS_A + n] = s;
}

__global__ __launch_bounds__(256, 4)
void vq_main(const float* __restrict__ z, const float* __restrict__ cb,
             float* __restrict__ ws, float* __restrict__ out) {
    __shared__ __align__(16) char smem[33792];
    float* zs    = (float*)smem;             // [CC][TN]  8 KB
    float* cbs   = (float*)(smem + 8192);    // [CC][TK]  8 KB
    float* red_d = (float*)(smem + 16384);   // [TN][16]  8 KB
    int*   red_i = (int*)(smem + 24576);     // [TN][16]  8 KB
    float* es    = (float*)smem;             // [32][256] epilogue (aliases above)
    int*   bi_s  = (int*)(smem + 32768);     // [TN]
    float* a_s   = (float*)(smem + 33280);   // [TN]

    const float* bsum = ws + WS_B;
    const float* a_g  = ws + WS_A;
    const float* cbT  = ws + WS_CBT;

    const int t  = threadIdx.x;
    const int ti = t & 15;
    const int tj = t >> 4;

    const int n0  = blockIdx.x * TN;
    const int b   = n0 >> 12;
    const int hw0 = n0 & 4095;
    const size_t zb = (size_t)b * DIMS * HWSZ;

    if (t < TN) a_s[t] = a_g[n0 + t];

    float run_d = 1e30f;
    int   run_i = 0;

    for (int kc = 0; kc < NKC; ++kc) {
        const int k0 = kc * TK;
        float acc[8][8];
#pragma unroll
        for (int i = 0; i < 8; ++i)
#pragma unroll
            for (int j = 0; j < 8; ++j) acc[i][j] = 0.0f;

        for (int ccI = 0; ccI < NCC; ++ccI) {
            const int c0 = ccI * CC;
            __syncthreads();
            // stage zs [16][128] : 2048 floats, 2 issues of float4
#pragma unroll
            for (int issue = 0; issue < 2; ++issue) {
                int f   = issue * 1024 + t * 4;
                int cl  = f >> 7;
                int col = f & 127;
                float4 v = *(const float4*)(z + zb + (size_t)(c0 + cl) * HWSZ + hw0 + col);
                *(float4*)(zs + cl * TN + col) = v;
            }
            // stage cbs [16][128]
#pragma unroll
            for (int issue = 0; issue < 2; ++issue) {
                int f   = issue * 1024 + t * 4;
                int cl  = f >> 7;
                int col = f & 127;
                float4 v = *(const float4*)(cbT + (size_t)(c0 + cl) * NCODES + k0 + col);
                *(float4*)(cbs + cl * TK + col) = v;
            }
            __syncthreads();
#pragma unroll
            for (int c = 0; c < CC; ++c) {
                const float4 za  = *(const float4*)(zs + c * TN + ti * 4);
                const float4 zb4 = *(const float4*)(zs + c * TN + 64 + ti * 4);
                const float4 ca  = *(const float4*)(cbs + c * TK + tj * 8);
                const float4 cb4 = *(const float4*)(cbs + c * TK + tj * 8 + 4);
                float zr[8] = {za.x, za.y, za.z, za.w, zb4.x, zb4.y, zb4.z, zb4.w};
                float cr[8] = {ca.x, ca.y, ca.z, ca.w, cb4.x, cb4.y, cb4.z, cb4.w};
#pragma unroll
                for (int i = 0; i < 8; ++i)
#pragma unroll
                    for (int j = 0; j < 8; ++j)
                        acc[i][j] = fmaf(zr[i], cr[j], acc[i][j]);
            }
        }

        // epilogue of k-chunk: d = (a + b) - 2*acc, local argmin, reduce
        float bfrag[8];
#pragma unroll
        for (int j = 0; j < 8; ++j) bfrag[j] = bsum[k0 + tj * 8 + j];

        __syncthreads();   // red arrays free from previous use
#pragma unroll
        for (int i = 0; i < 8; ++i) {
            const int nl = (i < 4) ? (ti * 4 + i) : (64 + ti * 4 + (i - 4));
            const float an = a_s[nl];
            float bd = 1e30f;
            int   bi = 0;
#pragma unroll
            for (int j = 0; j < 8; ++j) {
                const int kk = k0 + tj * 8 + j;
                float t1 = an + bfrag[j];
                float d  = t1 - 2.0f * acc[i][j];   // 2*acc exact; single round
                if (d < bd) { bd = d; bi = kk; }    // strict <: first index wins
            }
            red_d[nl * 16 + tj] = bd;
            red_i[nl * 16 + tj] = bi;
        }
        __syncthreads();
        if (t < TN) {
#pragma unroll 4
            for (int tj2 = 0; tj2 < 16; ++tj2) {
                float d2 = red_d[t * 16 + tj2];
                int   i2 = red_i[t * 16 + tj2];
                if (d2 < run_d) { run_d = d2; run_i = i2; }
            }
        }
    }

    if (t < TN) {
        bi_s[t] = run_i;
        out[(size_t)NPOS * DIMS + n0 + t] = (float)run_i;  // idx as float
    }

    // ---- epilogue: z_q write + loss, 4 passes of 32 rows staged in LDS ----
    float lpart = 0.0f;
    for (int pass = 0; pass < 4; ++pass) {
        const int tp = pass * 32;
        __syncthreads();
        for (int rr = 0; rr < 32; ++rr) {
            const int idx = bi_s[tp + rr];
            es[rr * 256 + (t ^ rr)] = cb[(size_t)idx * DIMS + t];  // XOR-swizzled store
        }
        __syncthreads();
#pragma unroll 4
        for (int r2 = 0; r2 < 32; ++r2) {
            const int fl2 = r2 * 256 + t;
            const int c   = fl2 >> 5;
            const int tnl = fl2 & 31;
            const float e = es[tnl * 256 + (c ^ tnl)];
            const size_t gz = zb + (size_t)c * HWSZ + hw0 + tp + tnl;
            const float zv = z[gz];
            const float diff = e - zv;          // fl(e - z)
            lpart = fmaf(diff, diff, lpart);
            out[gz] = zv + diff;                // fl(z + fl(e - z)) — straight-through
        }
    }

    // block-reduce loss partials
    for (int off = 32; off > 0; off >>= 1)
        lpart += __shfl_down(lpart, off);
    if ((t & 63) == 0) a_s[t >> 6] = lpart;     // a_s reuse, 4 waves
    __syncthreads();
    if (t == 0) {
        float s = a_s[0] + a_s[1] + a_s[2] + a_s[3];
        atomicAdd(ws + WS_LOSS, s);
    }
}

__global__ void loss_final(const float* __restrict__ ws, float* __restrict__ out) {
    float m = ws[WS_LOSS] / 16777216.0f;
    out[(size_t)NPOS * DIMS + NPOS] = m + 0.25f * m;
}

extern "C" void kernel_launch(void* const* d_in, const int* in_sizes, int n_in,
                              void* d_out, int out_size, void* d_ws, size_t ws_size,
                              hipStream_t stream) {
    (void)in_sizes; (void)n_in; (void)out_size; (void)ws_size;
    const float* z  = (const float*)d_in[0];
    const float* cb = (const float*)d_in[1];
    float* ws  = (float*)d_ws;
    float* out = (float*)d_out;

    prep_kernel<<<4, 256, 0, stream>>>(cb, ws);
    a_kernel<<<NPOS / 256, 256, 0, stream>>>(z, ws);
    vq_main<<<NPOS / TN, 256, 0, stream>>>(z, cb, ws, out);
    loss_final<<<1, 1, 0, stream>>>(ws, out);
}